// Round 10
// baseline (416.332 us; speedup 1.0000x reference)
//
#include <hip/hip_runtime.h>

#define Bn 512
#define Ln 2048
#define Kn 19
#define NEGV (-1000.0f)
#define START_IDn 17
#define PAD_IDn 18
#define SEG 64               // checkpoint segment (steps)
#define PBYTES 79691776u     // 512*2048*19*4

// ---------------------------------------------------------------------------
// R15: barrier-paced producer-consumer fusion (no spin-waits).
//   wave 0 (SIMD0, alone): byte-exact champion fwd for 2 batches.
//   waves 1-2 (SIMD1/2):   rec engines; per window each recs ONE segment as
//                          two concurrent 21-lane groups (both halves).
// __syncthreads every 2 fwd segments (17 windows) replaces R9/R10's volatile
// flag spinning — the suspected source of their ~85us dispatch overhead.
// This layout avoids BOTH prior tax mechanisms: no rec wave shares SIMD0
// with fwd (R10), and rec DS rate is ~half of R9's. Checkpoints live in LDS
// (dpck global deleted); backpointers staged in LDS, flushed to choice;
// proven crf_bwd unchanged. Same DP_CORE op order + exact max + first-index
// argmax => bit-identical output.
// ---------------------------------------------------------------------------

// per-step core (bit-exact, shared by fwd and rec): cand[p] = dp[p]+Trow[p],
// exact max tree.
#define DP_CORE(BASE)                                                          \
    float4 q0 = *(const float4*)((BASE) + 0);                                  \
    float4 q1 = *(const float4*)((BASE) + 4);                                  \
    float4 q2 = *(const float4*)((BASE) + 8);                                  \
    float4 q3 = *(const float4*)((BASE) + 12);                                 \
    float4 q4 = *(const float4*)((BASE) + 16); /* .w junk, unused */           \
    float cand[Kn];                                                            \
    cand[0]  = q0.x + Trow[0];  cand[1]  = q0.y + Trow[1];                     \
    cand[2]  = q0.z + Trow[2];  cand[3]  = q0.w + Trow[3];                     \
    cand[4]  = q1.x + Trow[4];  cand[5]  = q1.y + Trow[5];                     \
    cand[6]  = q1.z + Trow[6];  cand[7]  = q1.w + Trow[7];                     \
    cand[8]  = q2.x + Trow[8];  cand[9]  = q2.y + Trow[9];                     \
    cand[10] = q2.z + Trow[10]; cand[11] = q2.w + Trow[11];                    \
    cand[12] = q3.x + Trow[12]; cand[13] = q3.y + Trow[13];                    \
    cand[14] = q3.z + Trow[14]; cand[15] = q3.w + Trow[15];                    \
    cand[16] = q4.x + Trow[16]; cand[17] = q4.y + Trow[17];                    \
    cand[18] = q4.z + Trow[18];                                                \
    float m0 = fmaxf(fmaxf(cand[0],  cand[1]),  cand[2]);                      \
    float m1 = fmaxf(fmaxf(cand[3],  cand[4]),  cand[5]);                      \
    float m2 = fmaxf(fmaxf(cand[6],  cand[7]),  cand[8]);                      \
    float m3 = fmaxf(fmaxf(cand[9],  cand[10]), cand[11]);                     \
    float m4 = fmaxf(fmaxf(cand[12], cand[13]), cand[14]);                     \
    float m5 = fmaxf(fmaxf(cand[15], cand[16]), cand[17]);                     \
    float n0 = fmaxf(fmaxf(m0, m1), m2);                                       \
    float n1 = fmaxf(fmaxf(m3, m4), cand[18]);                                 \
    float best = fmaxf(fmaxf(n0, n1), m5);

// ---------------------------------------------------------------------------
__global__ __launch_bounds__(192, 1) void crf_fused(
    const float* __restrict__ P, const float* __restrict__ T,
    const int* __restrict__ mask, float* __restrict__ dpfin,
    int* __restrict__ lens, unsigned char* __restrict__ choice)
{
    const int tid = threadIdx.x;
    const int wv = tid >> 6;                   // 0 = fwd; 1,2 = rec engines
    const int lane = tid & 63;

    __shared__ float dpf[2][32];               // fwd DP round-trip
    __shared__ float ebuf[2][2][1280];         // fwd emission staging
    __shared__ float ckbuf[2][32][20];         // checkpoints [half][seg][tag]
    __shared__ float dpr[2][2][20];            // rec DP [recwave][half][tag20]
    __shared__ __align__(16) unsigned char rcbuf[2][2][1280]; // rec bp staging
    __shared__ int s_len2[2];

    // ---- fwd-wave state (persists across windows; live only on wave 0) ----
    const int half = lane >> 5;
    const int cF = lane & 31;
    const int bF = blockIdx.x * 2 + half;
    const int ccF = (cF < Kn) ? cF : (Kn - 1);
    int lmin = 0, mlen = 0, buf = 0, lenF = 0;
    float mydpF = NEGV;
    const unsigned bbyte = (unsigned)bF * (Ln * Kn * 4u);
    const unsigned limit = PBYTES - 16;
    const char* Pc = (const char*)P;
    float4 r[10];

    // ---- rec-engine state ----
    const int rw = wv - 1;                     // 0,1 (valid when wv>=1)
    const int g = lane / 21;                   // 0,1 active; 2,3 idle lanes
    const int cR = lane - g * 21;              // 0..20 within group
    const bool gv = (g < 2);
    const int h = gv ? g : 1;                  // group == batch half
    const int bR = blockIdx.x * 2 + h;
    const int ccR = (cR < Kn) ? cR : (Kn - 1);

    // shared Trow registers: tag row for this lane's role
    const int cidx = (wv == 0) ? ccF : ccR;
    float Trow[Kn];
#pragma unroll
    for (int p = 0; p < Kn; ++p) Trow[p] = T[cidx * Kn + p];

#define STAGE_LOAD(ci)                                                         \
    { unsigned base_ = bbyte + (unsigned)(ci) * 4864u + ((unsigned)cF << 4);   \
      _Pragma("unroll")                                                        \
      for (int i_ = 0; i_ < 10; ++i_) {                                        \
          unsigned o_ = base_ + (unsigned)i_ * 512u;                           \
          if (o_ > limit) o_ = limit;                                          \
          r[i_] = *(const float4*)(Pc + o_);                                   \
      } }
#define STAGE_WRITE(nb)                                                        \
    { float* d_ = &ebuf[nb][half][(unsigned)cF << 2];                          \
      _Pragma("unroll")                                                        \
      for (int i_ = 0; i_ < 10; ++i_) *(float4*)(d_ + i_ * 128) = r[i_]; }

    if (wv == 0) {
        __builtin_amdgcn_s_setprio(1);         // protect the serial chain
        // length = popcount of contiguous-prefix mask row (champion-exact)
        const int* mrow = mask + (size_t)bF * Ln;
        int sum = 0;
#pragma unroll
        for (int j = 0; j < Ln / 128; ++j) {
            int4 v = *(const int4*)(mrow + j * 128 + cF * 4);
            sum += v.x + v.y + v.z + v.w;
        }
#pragma unroll
        for (int k = 1; k < 32; k <<= 1) sum += __shfl_xor(sum, k, 64);
        lenF = sum;
        if (cF == 0) { lens[bF] = lenF; s_len2[half] = lenF; }
        const int lenO = __shfl_xor(lenF, 32, 64);
        int maxlen = lenF > lenO ? lenF : lenO;
        int lm = lenF < lenO ? lenF : lenO;
        lmin = __builtin_amdgcn_readfirstlane(lm);
        int ml = (maxlen + (SEG - 1)) & ~(SEG - 1);
        mlen = __builtin_amdgcn_readfirstlane(ml);

        mydpF = (cF == START_IDn) ? 0.0f : NEGV;
        dpf[half][cF] = mydpF;

        STAGE_LOAD(0);
        STAGE_WRITE(0);
    }
    __syncthreads();                           // s_len2 visible to all waves

    const int len0 = s_len2[0], len1 = s_len2[1];
    const int lenR = (h == 0) ? len0 : len1;
    const int lenmax = (len0 > len1) ? len0 : len1;

    // ---- 17 windows: fwd does segs {2w,2w+1}; rec does seg 2(w-1)+rw ------
    for (int w = 0; w < 17; ++w) {
        if (wv == 0) {
            if (w < 16) {
#pragma unroll 1
                for (int s2 = 0; s2 < 2; ++s2) {
                    const int sg = 2 * w + s2;
                    const int t0 = sg * SEG;
                    if (t0 < mlen) {
                        // checkpoint: DP entering step t0
                        if (cF < Kn) ckbuf[half][sg][cF] = mydpF;
                        STAGE_LOAD(sg + 1);    // prefetch next segment
                        const float* ebl = &ebuf[buf][half][0];

                        if (t0 + SEG <= lmin) {
                            for (int tt = 0; tt < SEG; tt += 8) {
#pragma unroll
                                for (int u = 0; u < 8; ++u) {
                                    const float e = ebl[(tt + u) * Kn + ccF];
                                    const float* base_ = &dpf[half][0];
                                    DP_CORE(base_)
                                    mydpF = best + e;
                                    dpf[half][cF] = mydpF;
                                }
                            }
                        } else {
                            for (int tt = 0; tt < SEG; tt += 8) {
#pragma unroll
                                for (int u = 0; u < 8; ++u) {
                                    const int t = t0 + tt + u;
                                    const float e = ebl[(tt + u) * Kn + ccF];
                                    const float* base_ = &dpf[half][0];
                                    DP_CORE(base_)
                                    float nd = best + e;
                                    mydpF = (t < lenF) ? nd : mydpF;
                                    dpf[half][cF] = mydpF;
                                }
                            }
                        }
                        STAGE_WRITE(buf ^ 1);
                        buf ^= 1;
                    }
                }
            }
        } else if (w >= 1) {
            const int sg = 2 * (w - 1) + rw;   // segment recomputed this window
            const int t0 = sg * SEG;
            if (t0 < lenmax) {
                const bool active = gv && (t0 < lenR);
                float mydp = (active && cR < Kn) ? ckbuf[h][sg][cR] : NEGV;
                if (active && cR < Kn) dpr[rw][h][cR] = mydp;
                const float* prow = P + (size_t)bR * Ln * Kn + (size_t)t0 * Kn;

                // rolling emission prefetch (depth 8)
                float eb[8];
#pragma unroll
                for (int u = 0; u < 8; ++u) eb[u] = prow[u * Kn + ccR];

                for (int tt = 0; tt < SEG; tt += 8) {
#pragma unroll
                    for (int u = 0; u < 8; ++u) {
                        const int t = t0 + tt + u;
                        const float e = eb[u];
                        const float* base_ = &dpr[rw][h][0];
                        DP_CORE(base_)
                        float nd = best + e;
                        mydp = (t < lenR) ? nd : mydp;
                        if (active && cR < Kn) dpr[rw][h][cR] = mydp;

                        // first-index argmax (jnp.argmax tie-break)
                        int arg = Kn - 1;
#pragma unroll
                        for (int p = Kn - 2; p >= 0; --p)
                            arg = (cand[p] == best) ? p : arg;
                        if (active && cR < Kn)
                            rcbuf[rw][h][(tt + u) * Kn + cR] = (unsigned char)arg;

                        // prefetch emission for step tt+u+8 (clamped)
                        int tn = tt + u + 8;
                        int tloc = (t0 + tn < Ln) ? tn : (Ln - 1 - t0);
                        eb[u] = prow[tloc * Kn + ccR];
                    }
                }
                // bulk flush this segment's backpointers to global
                if (active) {
                    const int4* s4 = (const int4*)&rcbuf[rw][h][0];
                    int4* d4 = (int4*)(choice + (size_t)bR * Ln * Kn + (size_t)t0 * Kn);
                    for (int i = cR; i < (SEG * Kn) / 16; i += 21) d4[i] = s4[i];
                }
            }
        }
        __syncthreads();
    }
    if (wv == 0 && cF < Kn) dpfin[bF * Kn + cF] = mydpF;
#undef STAGE_LOAD
#undef STAGE_WRITE
}

// ---------------------------------------------------------------------------
// Backtrace: verbatim proven kernel (exact integer function-composition scan).
// ---------------------------------------------------------------------------
__global__ __launch_bounds__(384, 1) void crf_bwd(
    const float* __restrict__ T, const unsigned char* __restrict__ choice,
    const float* __restrict__ dpfin, const int* __restrict__ lens,
    int* __restrict__ out)
{
    __shared__ unsigned char comp[Ln * Kn];   // 38912 B
    __shared__ int vchain[17];
    __shared__ int s_last, s_len;

    const int b = blockIdx.x;
    const int tid = threadIdx.x;

    {
        const int4* src = (const int4*)(choice + (size_t)b * Ln * Kn);
        int4* dst = (int4*)comp;
        for (int i = tid; i < (Ln * Kn) / 16; i += 384) dst[i] = src[i];
    }
    if (tid == 0) {
        s_len = lens[b];
        float bestv = dpfin[b * Kn + 0] + T[PAD_IDn * Kn + 0];
        int bl = 0;
        for (int ci = 1; ci < Kn; ++ci) {
            float v = dpfin[b * Kn + ci] + T[PAD_IDn * Kn + ci];
            if (v > bestv) { bestv = v; bl = ci; }
        }
        s_last = bl;
    }
    __syncthreads();
    const int len = s_len;

    // Phase 1: suffix-compose within each 128-step chunk, in place.
    {
        const int wv = tid >> 6;
        const int lane = tid & 63;
        const int ch = wv * 3 + lane / Kn;
        const int c = lane % Kn;
        if (lane < 3 * Kn && ch < 16) {
            int cur = c;
            const int tb = ch * 128 + 127;
            for (int i = 0; i < 128; ++i) {
                const int t = tb - i;
                int nv = comp[t * Kn + cur];   // cur <= 18 always: in-bounds
                cur = (t < len) ? nv : cur;
                comp[t * Kn + c] = cur;
            }
        }
    }
    __syncthreads();

    // Phase 2: chunk-boundary chain
    if (tid == 0) {
        int v = s_last;
        vchain[16] = v;
        for (int ch = 15; ch >= 0; --ch) {
            v = comp[ch * 128 * Kn + v];
            vchain[ch] = v;
        }
    }
    __syncthreads();

    // Phase 3: emit path
    const int last = s_last;
    int* orow = out + (size_t)b * Ln;
    for (int t = tid; t < Ln; t += 384) {
        int val;
        if (t >= len) {
            val = -1;
        } else if (t == Ln - 1) {
            val = last;
        } else {
            const int tp = t + 1;
            const int vc = vchain[(tp >> 7) + 1];
            val = comp[tp * Kn + vc];
        }
        orow[t] = val;
    }
}

// ---------------------------------------------------------------------------
extern "C" void kernel_launch(void* const* d_in, const int* in_sizes, int n_in,
                              void* d_out, int out_size, void* d_ws, size_t ws_size,
                              hipStream_t stream)
{
    const float* P    = (const float*)d_in[0];
    const float* T    = (const float*)d_in[1];
    const int*   mask = (const int*)d_in[2];
    int* out = (int*)d_out;

    // workspace layout — original proven footprint (19,963,904 B):
    // choice at 0, dpfin, lens. dpck no longer exists (checkpoints in LDS).
    const size_t choice_bytes = (size_t)Bn * Ln * Kn;            // 19,922,944
    unsigned char* choice = (unsigned char*)d_ws;
    float* dpfin = (float*)((char*)d_ws + choice_bytes);         // 38,912 B
    int* lens = (int*)((char*)d_ws + choice_bytes + (size_t)Bn * Kn * 4);

    crf_fused<<<Bn / 2, 192, 0, stream>>>(P, T, mask, dpfin, lens, choice);
    crf_bwd<<<Bn, 384, 0, stream>>>(T, choice, dpfin, lens, out);
}

// Round 11
// 349.203 us; speedup vs baseline: 1.1922x; 1.1922x over previous
//
#include <hip/hip_runtime.h>

#define Bn 512
#define Ln 2048
#define Kn 19
#define NEGV (-1000.0f)
#define START_IDn 17
#define PAD_IDn 18
#define SEG 64               // checkpoint / staging segment (steps)
#define PBYTES 79691776u     // 512*2048*19*4

// ---------------------------------------------------------------------------
// R16 = R14 (champion 377.6us) + packed-f32 cand adds in DP_CORE.
// Fit across R5-R12: lone-wave fwd wall = instr/step x ~6.5cy REGARDLESS of
// instruction type (DS/DPP/VALU/SALU) => issue-cadence-bound, and the only
// lever is instruction count. 19 scalar cand adds -> 9 v_pk_add_f32 + 1
// scalar (clang ext_vector float2 => <2 x float> fadd => pk op on gfx950;
// b128 results give aligned x,y / z,w pairs). Packed adds are bit-identical
// IEEE adds; exact-max tree unchanged => DP/checkpoints/argmax bit-identical.
// Same macro in fwd and rec preserves cross-kernel bit-exactness. All else
// byte-identical to R14. Downside-bounded (no packing => same scalar adds).
// P-C fusion abandoned: R15 confirmed a rare ~18.5ms pathological dispatch
// (60x) in every co-resident structure; tail risk kills the mean.
// ---------------------------------------------------------------------------

typedef float v2f __attribute__((ext_vector_type(2)));

// per-step core (bit-exact, shared by fwd and rec): cand[p] = dp[p]+Trow[p]
// via packed pairs, exact max tree (same shape as champion).
// Requires in scope: v2f Tw[9]; float T18;
#define DP_CORE(BASE)                                                          \
    float4 q0 = *(const float4*)((BASE) + 0);                                  \
    float4 q1 = *(const float4*)((BASE) + 4);                                  \
    float4 q2 = *(const float4*)((BASE) + 8);                                  \
    float4 q3 = *(const float4*)((BASE) + 12);                                 \
    float4 q4 = *(const float4*)((BASE) + 16); /* .w junk, unused */           \
    v2f c01 = *(const v2f*)&q0.x + Tw[0];                                      \
    v2f c23 = *(const v2f*)&q0.z + Tw[1];                                      \
    v2f c45 = *(const v2f*)&q1.x + Tw[2];                                      \
    v2f c67 = *(const v2f*)&q1.z + Tw[3];                                      \
    v2f c89 = *(const v2f*)&q2.x + Tw[4];                                      \
    v2f cAB = *(const v2f*)&q2.z + Tw[5];                                      \
    v2f cCD = *(const v2f*)&q3.x + Tw[6];                                      \
    v2f cEF = *(const v2f*)&q3.z + Tw[7];                                      \
    v2f cGH = *(const v2f*)&q4.x + Tw[8];                                      \
    float cand[Kn];                                                            \
    cand[0]  = c01.x; cand[1]  = c01.y; cand[2]  = c23.x; cand[3]  = c23.y;    \
    cand[4]  = c45.x; cand[5]  = c45.y; cand[6]  = c67.x; cand[7]  = c67.y;    \
    cand[8]  = c89.x; cand[9]  = c89.y; cand[10] = cAB.x; cand[11] = cAB.y;    \
    cand[12] = cCD.x; cand[13] = cCD.y; cand[14] = cEF.x; cand[15] = cEF.y;    \
    cand[16] = cGH.x; cand[17] = cGH.y; cand[18] = q4.z + T18;                 \
    float m0 = fmaxf(fmaxf(cand[0],  cand[1]),  cand[2]);                      \
    float m1 = fmaxf(fmaxf(cand[3],  cand[4]),  cand[5]);                      \
    float m2 = fmaxf(fmaxf(cand[6],  cand[7]),  cand[8]);                      \
    float m3 = fmaxf(fmaxf(cand[9],  cand[10]), cand[11]);                     \
    float m4 = fmaxf(fmaxf(cand[12], cand[13]), cand[14]);                     \
    float m5 = fmaxf(fmaxf(cand[15], cand[16]), cand[17]);                     \
    float n0 = fmaxf(fmaxf(m0, m1), m2);                                       \
    float n1 = fmaxf(fmaxf(m3, m4), cand[18]);                                 \
    float best = fmaxf(fmaxf(n0, n1), m5);

// load the transition row for output tag `CIDX` into Tw/T18 pairs
#define LOAD_TROW(CIDX)                                                        \
    v2f Tw[9]; float T18;                                                      \
    _Pragma("unroll")                                                          \
    for (int p_ = 0; p_ < 9; ++p_) {                                           \
        Tw[p_].x = T[(CIDX) * Kn + 2 * p_];                                    \
        Tw[p_].y = T[(CIDX) * Kn + 2 * p_ + 1];                                \
    }                                                                          \
    T18 = T[(CIDX) * Kn + 18];

// ---------------------------------------------------------------------------
// FWD: champion structure (2 batches per wave), pk-add core.
// ---------------------------------------------------------------------------
__global__ __launch_bounds__(64, 1) void crf_fwd(
    const float* __restrict__ P, const float* __restrict__ T,
    const int* __restrict__ mask, float* __restrict__ dpck,
    float* __restrict__ dpfin, int* __restrict__ lens)
{
    const int lane = threadIdx.x;
    const int half = lane >> 5;
    const int c = lane & 31;
    const int b = blockIdx.x * 2 + half;
    const int cc = (c < Kn) ? c : (Kn - 1);

    LOAD_TROW(cc)

    // length = popcount of contiguous-prefix mask row
    const int* mrow = mask + (size_t)b * Ln;
    int sum = 0;
#pragma unroll
    for (int j = 0; j < Ln / 128; ++j) {
        int4 v = *(const int4*)(mrow + j * 128 + c * 4);
        sum += v.x + v.y + v.z + v.w;
    }
#pragma unroll
    for (int k = 1; k < 32; k <<= 1) sum += __shfl_xor(sum, k, 64);
    const int len = sum;
    if (c == 0) lens[b] = len;
    const int lenO = __shfl_xor(len, 32, 64);
    int maxlen = len > lenO ? len : lenO;
    int lmin = len < lenO ? len : lenO;
    lmin = __builtin_amdgcn_readfirstlane(lmin);
    int mlen = (maxlen + (SEG - 1)) & ~(SEG - 1);
    mlen = __builtin_amdgcn_readfirstlane(mlen);

    __shared__ float dp[2][32];
    __shared__ float ebuf[2][2][1280];   // [buf][half]; 64*19=1216 used + pad

    float mydp = (c == START_IDn) ? 0.0f : NEGV;
    dp[half][c] = mydp;

    const unsigned bbyte = (unsigned)b * (Ln * Kn * 4u);
    const unsigned limit = PBYTES - 16;
    const char* Pc = (const char*)P;
    float4 r[10];

#define STAGE_LOAD(ci)                                                         \
    { unsigned base_ = bbyte + (unsigned)(ci) * 4864u + ((unsigned)c << 4);    \
      _Pragma("unroll")                                                        \
      for (int i_ = 0; i_ < 10; ++i_) {                                        \
          unsigned o_ = base_ + (unsigned)i_ * 512u;                           \
          if (o_ > limit) o_ = limit;                                          \
          r[i_] = *(const float4*)(Pc + o_);                                   \
      } }
#define STAGE_WRITE(nb)                                                        \
    { float* d_ = &ebuf[nb][half][(unsigned)c << 2];                           \
      _Pragma("unroll")                                                        \
      for (int i_ = 0; i_ < 10; ++i_) *(float4*)(d_ + i_ * 128) = r[i_]; }

    int buf = 0;
    STAGE_LOAD(0);
    STAGE_WRITE(0);

    for (int t0 = 0; t0 < mlen; t0 += SEG) {
        // checkpoint: DP entering step t0 (includes initial DP at t0=0)
        if (c < Kn)
            dpck[((unsigned)b * 32u + (unsigned)(t0 >> 6)) * (unsigned)Kn + (unsigned)c] = mydp;
        STAGE_LOAD((t0 >> 6) + 1);       // prefetch next segment's emissions
        const float* ebl = &ebuf[buf][half][0];

        if (t0 + SEG <= lmin) {
            // fast path: every step strictly below both lengths — no mask
            for (int tt = 0; tt < SEG; tt += 8) {
#pragma unroll
                for (int u = 0; u < 8; ++u) {
                    const float e = ebl[(tt + u) * Kn + cc];
                    const float* base_ = &dp[half][0];
                    DP_CORE(base_)
                    mydp = best + e;
                    dp[half][c] = mydp;
                }
            }
        } else {
            for (int tt = 0; tt < SEG; tt += 8) {
#pragma unroll
                for (int u = 0; u < 8; ++u) {
                    const int t = t0 + tt + u;
                    const float e = ebl[(tt + u) * Kn + cc];
                    const float* base_ = &dp[half][0];
                    DP_CORE(base_)
                    float nd = best + e;
                    mydp = (t < len) ? nd : mydp;   // frozen past sequence end
                    dp[half][c] = mydp;
                }
            }
        }
        STAGE_WRITE(buf ^ 1);
        buf ^= 1;
    }
    if (c < Kn) dpfin[b * Kn + c] = mydp;
#undef STAGE_LOAD
#undef STAGE_WRITE
}

// ---------------------------------------------------------------------------
// Fused rec+bwd (R14 structure): one 704-thread block (11 waves) per batch.
// Phase R = 32 segments in 21-lane groups, 3 per wave; bit-exact recompute
// from checkpoints, backpointers straight into comp[] (LDS). Then the proven
// backtrace phases 1-3.
// ---------------------------------------------------------------------------
__global__ __launch_bounds__(704, 1) void crf_recbwd(
    const float* __restrict__ P, const float* __restrict__ T,
    const float* __restrict__ dpck, const float* __restrict__ dpfin,
    const int* __restrict__ lens, int* __restrict__ out)
{
    const int b = blockIdx.x;
    const int tid = threadIdx.x;
    const int len = lens[b];

    __shared__ unsigned char comp[Ln * Kn];     // 38912 B: bp, then composed
    __shared__ float dp[32][20];                // 20-float rows: 80B, b128-ok
    __shared__ int vchain[17];
    __shared__ int s_last;

    // ---------------- Phase R: recompute backpointers into comp ------------
    {
        const int w = tid >> 6;                 // wave 0..10
        const int lane64 = tid & 63;
        const int g = lane64 / 21;              // group 0..3 (3 = idle lane 63)
        const int c = lane64 - g * 21;          // 0..20 within group
        const int seg0 = w * 3 + g;             // 0..32
        const bool gvalid = (g < 3) && (seg0 < 32);
        const int seg = gvalid ? seg0 : 31;     // clamped for safe addressing
        const int cc = (c < Kn) ? c : (Kn - 1);
        const int t0 = seg * SEG;
        const bool active = gvalid && (t0 < len);

        LOAD_TROW(cc)

        float mydp = (active && c < Kn)
            ? dpck[((unsigned)b * 32u + (unsigned)seg) * (unsigned)Kn + (unsigned)c]
            : NEGV;
        if (active && c < Kn) dp[seg][c] = mydp;

        const float* prow = P + (size_t)b * Ln * Kn + (size_t)t0 * Kn;

        // rolling emission prefetch (depth 8)
        float eb[8];
#pragma unroll
        for (int u = 0; u < 8; ++u) eb[u] = prow[u * Kn + cc];

        for (int tt = 0; tt < SEG; tt += 8) {
#pragma unroll
            for (int u = 0; u < 8; ++u) {
                const int t = t0 + tt + u;
                const float e = eb[u];
                const float* base_ = &dp[seg][0];
                DP_CORE(base_)
                float nd = best + e;
                mydp = (t < len) ? nd : mydp;
                if (active && c < Kn) dp[seg][c] = mydp;

                // first-index argmax (jnp.argmax tie-break), exact equality
                int arg = Kn - 1;
#pragma unroll
                for (int p = Kn - 2; p >= 0; --p)
                    arg = (cand[p] == best) ? p : arg;
                if (active && c < Kn) comp[t * Kn + c] = (unsigned char)arg;

                // prefetch emission for local step tt+u+8 (clamped in-bounds)
                int tn = tt + u + 8;
                int tloc = (t0 + tn < Ln) ? tn : (Ln - 1 - t0);
                eb[u] = prow[tloc * Kn + cc];
            }
        }
    }
    // rows t >= len are uninitialized LDS: read-then-discarded below (values
    // never used as indices), exactly as the proven bwd handled garbage rows.

    if (tid == 0) {
        float bestv = dpfin[b * Kn + 0] + T[PAD_IDn * Kn + 0];
        int bl = 0;
        for (int ci = 1; ci < Kn; ++ci) {
            float v = dpfin[b * Kn + ci] + T[PAD_IDn * Kn + ci];
            if (v > bestv) { bestv = v; bl = ci; }
        }
        s_last = bl;
    }
    __syncthreads();

    // ---- Phase 1: suffix-compose within each 128-step chunk, in place.
    // Proven mapping: 3 chunk-groups of 19 lanes per wave; chunk groups never
    // cross a wave => lockstep read-before-write preserved.
    {
        const int wv = tid >> 6;
        const int lane2 = tid & 63;
        const int ch = wv * 3 + lane2 / Kn;
        const int c2 = lane2 % Kn;
        if (lane2 < 3 * Kn && ch < 16) {
            int cur = c2;
            const int tb = ch * 128 + 127;
            for (int i = 0; i < 128; ++i) {
                const int t = tb - i;
                int nv = comp[t * Kn + cur];     // cur <= 18 always: in-bounds
                cur = (t < len) ? nv : cur;
                comp[t * Kn + c2] = cur;
            }
        }
    }
    __syncthreads();

    // ---- Phase 2: chunk-boundary chain
    if (tid == 0) {
        int v = s_last;
        vchain[16] = v;
        for (int ch = 15; ch >= 0; --ch) {
            v = comp[ch * 128 * Kn + v];
            vchain[ch] = v;
        }
    }
    __syncthreads();

    // ---- Phase 3: emit path
    const int last = s_last;
    int* orow = out + (size_t)b * Ln;
    for (int t = tid; t < Ln; t += 704) {
        int val;
        if (t >= len) {
            val = -1;
        } else if (t == Ln - 1) {
            val = last;
        } else {
            const int tp = t + 1;
            const int vc = vchain[(tp >> 7) + 1];
            val = comp[tp * Kn + vc];
        }
        orow[t] = val;
    }
}

// ---------------------------------------------------------------------------
extern "C" void kernel_launch(void* const* d_in, const int* in_sizes, int n_in,
                              void* d_out, int out_size, void* d_ws, size_t ws_size,
                              hipStream_t stream)
{
    const float* P    = (const float*)d_in[0];
    const float* T    = (const float*)d_in[1];
    const int*   mask = (const int*)d_in[2];
    int* out = (int*)d_out;

    // workspace layout — identical proven footprint (19,963,904 B). dpck
    // (1,245,184 B) at ws head (old choice region); dpfin/lens proven offsets.
    const size_t choice_bytes = (size_t)Bn * Ln * Kn;            // 19,922,944
    float* dpck  = (float*)d_ws;
    float* dpfin = (float*)((char*)d_ws + choice_bytes);         // 38,912 B
    int* lens = (int*)((char*)d_ws + choice_bytes + (size_t)Bn * Kn * 4);

    crf_fwd<<<Bn / 2, 64, 0, stream>>>(P, T, mask, dpck, dpfin, lens);
    crf_recbwd<<<Bn, 704, 0, stream>>>(P, T, dpck, dpfin, lens, out);
}